// Round 2
// baseline (267.749 us; speedup 1.0000x reference)
//
#include <hip/hip_runtime.h>
#include <cstddef>

#define BATCH 4
#define SEQ   4096
#define DIM   2048
#define EPSF  1e-5f
#define TCHUNK 16
#define CPB   (SEQ / TCHUNK)         // 256 chunks per batch
#define NBLK  (BATCH * CPB)          // 1024 blocks

__device__ __forceinline__ float wave_sum(float v) {
#pragma unroll
    for (int off = 32; off > 0; off >>= 1)
        v += __shfl_down(v, off, 64);
    return v;
}

// Phase 1: fused rmsnorm -> causal depthwise conv(W=4) -> silu -> (p1-p0) dot
// -> sign. gate>0.5 <=> logit1-logit0>0, so only the sign of one fused dot is
// needed. One block owns all D=2048 (256 thr x 8 ch) and slides over TCHUNK
// tokens, carrying the 3-token normalized history in registers.
// Tokens processed in groups of 4 with write-once LDS slots and a deferred
// mask write: 6 barriers per chunk (vs 38 in the per-token version).
// Writes ONLY tok[b*S+s] = selected ? 0x8000 : 0   (u16, 32KB total d_ws).
__global__ __launch_bounds__(256, 3) void mask_kernel(
    const float* __restrict__ x, const float* __restrict__ nw,
    const float* __restrict__ cw, const float* __restrict__ pw,
    unsigned short* __restrict__ tok)
{
    __shared__ float lds_ss[5][4][4];   // [group(4=warmup)][tok-in-group][wave]
    __shared__ float lds_acc[4][4][4];  // write-once slots -> no WAR hazards

    const int t = threadIdx.x, lane = t & 63, wid = t >> 6;
    // XCD swizzle: seq-adjacent chunks -> same XCD (L2 reuse of warm-up rows)
    const int G = gridDim.x;
    const int chunk = (blockIdx.x & 7) * (G >> 3) + (blockIdx.x >> 3);
    const int b  = chunk / CPB;
    const int s0 = (chunk % CPB) * TCHUNK;
    const int d0 = 4 * t, d1 = d0 + 1024;

    // conv*norm folded (cwn), projection diff (pd)
    float cwn[8][4], pd[8];
    {
        float4 n0 = *(const float4*)(nw + d0);
        float4 n1 = *(const float4*)(nw + d1);
        float nv[8] = {n0.x, n0.y, n0.z, n0.w, n1.x, n1.y, n1.z, n1.w};
#pragma unroll
        for (int i = 0; i < 8; ++i) {
            const int d = (i < 4) ? (d0 + i) : (d1 + i - 4);
            float4 c4 = *(const float4*)(cw + 4 * d);
            cwn[i][0] = c4.x * nv[i]; cwn[i][1] = c4.y * nv[i];
            cwn[i][2] = c4.z * nv[i]; cwn[i][3] = c4.w * nv[i];
        }
        float4 a0 = *(const float4*)(pw + d0);
        float4 a1 = *(const float4*)(pw + d1);
        float4 b0 = *(const float4*)(pw + DIM + d0);
        float4 b1 = *(const float4*)(pw + DIM + d1);
        pd[0] = b0.x - a0.x; pd[1] = b0.y - a0.y; pd[2] = b0.z - a0.z; pd[3] = b0.w - a0.w;
        pd[4] = b1.x - a1.x; pd[5] = b1.y - a1.y; pd[6] = b1.z - a1.z; pd[7] = b1.w - a1.w;
    }

    const float* xb = x + (size_t)b * SEQ * DIM;
    float h1[8], h2[8], h3[8];   // normalized rows s-1, s-2, s-3

    // ---- warm-up: tokens s0-3..s0-1 (1 barrier) ----
    {
        float wv[3][8];
#pragma unroll
        for (int w = 0; w < 3; ++w) {
            const int s = s0 - 3 + w;
            if (s >= 0) {
                float4 a = *(const float4*)(xb + (size_t)s * DIM + d0);
                float4 c = *(const float4*)(xb + (size_t)s * DIM + d1);
                wv[w][0]=a.x; wv[w][1]=a.y; wv[w][2]=a.z; wv[w][3]=a.w;
                wv[w][4]=c.x; wv[w][5]=c.y; wv[w][6]=c.z; wv[w][7]=c.w;
            } else {
#pragma unroll
                for (int i = 0; i < 8; ++i) wv[w][i] = 0.f;
            }
            float ss = 0.f;
#pragma unroll
            for (int i = 0; i < 8; ++i) ss += wv[w][i] * wv[w][i];
            ss = wave_sum(ss);
            if (lane == 0) lds_ss[4][w][wid] = ss;
        }
        __syncthreads();
#pragma unroll
        for (int w = 0; w < 3; ++w) {
            const float sum4 = lds_ss[4][w][0] + lds_ss[4][w][1]
                             + lds_ss[4][w][2] + lds_ss[4][w][3];
            const float rstd = 1.0f / sqrtf(sum4 * (1.0f / DIM) + EPSF);
            float* h = (w == 0) ? h3 : (w == 1) ? h2 : h1;
#pragma unroll
            for (int i = 0; i < 8; ++i) h[i] = wv[w][i] * rstd;
        }
    }

    // ---- main: 4 groups of 4 tokens, 1 barrier each + 1 final ----
    int pending = -1;
#pragma unroll
    for (int g = 0; g < 4; ++g) {
        float xv[4][8];
#pragma unroll
        for (int j = 0; j < 4; ++j) {
            const int s = s0 + 4 * g + j;
            float4 a = *(const float4*)(xb + (size_t)s * DIM + d0);
            float4 c = *(const float4*)(xb + (size_t)s * DIM + d1);
            xv[j][0]=a.x; xv[j][1]=a.y; xv[j][2]=a.z; xv[j][3]=a.w;
            xv[j][4]=c.x; xv[j][5]=c.y; xv[j][6]=c.z; xv[j][7]=c.w;
        }
#pragma unroll
        for (int j = 0; j < 4; ++j) {
            float ss = 0.f;
#pragma unroll
            for (int i = 0; i < 8; ++i) ss += xv[j][i] * xv[j][i];
            ss = wave_sum(ss);
            if (lane == 0) lds_ss[g][j][wid] = ss;
        }
        __syncthreads();   // orders: this group's ss writes; prev group's acc writes
        if (pending >= 0 && t < 4) {
            const float a = lds_acc[pending][t][0] + lds_acc[pending][t][1]
                          + lds_acc[pending][t][2] + lds_acc[pending][t][3];
            tok[b * SEQ + s0 + 4 * pending + t] = (a > 0.f) ? 0x8000 : 0;
        }
#pragma unroll
        for (int j = 0; j < 4; ++j) {
            const float sum4 = lds_ss[g][j][0] + lds_ss[g][j][1]
                             + lds_ss[g][j][2] + lds_ss[g][j][3];
            const float rstd = 1.0f / sqrtf(sum4 * (1.0f / DIM) + EPSF);
            float acc = 0.f;
#pragma unroll
            for (int i = 0; i < 8; ++i) {
                const float hc = xv[j][i] * rstd;
                const float y = cwn[i][0] * h3[i] + cwn[i][1] * h2[i]
                              + cwn[i][2] * h1[i] + cwn[i][3] * hc;
                const float sig = 1.0f / (1.0f + __expf(-y));
                acc += (y * sig) * pd[i];
                h3[i] = h2[i]; h2[i] = h1[i]; h1[i] = hc;
            }
            acc = wave_sum(acc);
            if (lane == 0) lds_acc[g][j][wid] = acc;
        }
        pending = g;
    }
    __syncthreads();
    if (t < 4) {
        const float a = lds_acc[3][t][0] + lds_acc[3][t][1]
                      + lds_acc[3][t][2] + lds_acc[3][t][3];
        tok[b * SEQ + s0 + 12 + t] = (a > 0.f) ? 0x8000 : 0;
    }
}

// Phase 2: per-batch inclusive prefix over the selected bits, packed back into
// the SAME u16: bit15 = selected, bits 0..12 = inclusive prefix p[s] (<=4096).
__global__ __launch_bounds__(256) void scan_kernel(unsigned short* __restrict__ tok)
{
    const int b = blockIdx.x, t = threadIdx.x;
    const int PER = SEQ / 256;   // 16
    __shared__ int wtot[4];

    int m[PER], tot = 0;
#pragma unroll
    for (int i = 0; i < PER; ++i) {
        m[i] = tok[b * SEQ + t * PER + i] >> 15;
        tot += m[i];
    }
    const int lane = t & 63, wid = t >> 6;
    int inc = tot;
#pragma unroll
    for (int off = 1; off < 64; off <<= 1) {
        int v = __shfl_up(inc, off, 64);
        if (lane >= off) inc += v;
    }
    if (lane == 63) wtot[wid] = inc;
    __syncthreads();
    int pref = inc - tot;
    for (int w = 0; w < wid; ++w) pref += wtot[w];

    int run = pref;
#pragma unroll
    for (int i = 0; i < PER; ++i) {
        run += m[i];
        tok[b * SEQ + t * PER + i] = (unsigned short)((m[i] << 15) | run);
    }
}

// Phase 3: source-driven scatter. Token (b,s): selected -> dest = p-1 (copy x
// row); unselected -> dest = nsel + s - p (zero row). Bijection onto [0,S):
// every output row written exactly once (d_out is poisoned each call).
__global__ __launch_bounds__(256) void scatter_kernel(
    const float* __restrict__ x, const unsigned short* __restrict__ tok,
    float* __restrict__ out)
{
    const int b = blockIdx.x / SEQ;
    const int s = blockIdx.x - b * SEQ;
    const int t = threadIdx.x;
    const unsigned v    = tok[b * SEQ + s];
    const int     nsel  = tok[b * SEQ + SEQ - 1] & 0x7FFF;
    const int     p     = v & 0x7FFF;
    const int     dest  = (v & 0x8000u) ? (p - 1) : (nsel + s - p);
    float* o = out + ((size_t)b * SEQ + dest) * DIM;
    if (v & 0x8000u) {
        const float* src = x + ((size_t)b * SEQ + s) * DIM;
        *(float4*)(o + 4 * t)        = *(const float4*)(src + 4 * t);
        *(float4*)(o + 4 * t + 1024) = *(const float4*)(src + 4 * t + 1024);
    } else {
        const float4 z = make_float4(0.f, 0.f, 0.f, 0.f);
        *(float4*)(o + 4 * t)        = z;
        *(float4*)(o + 4 * t + 1024) = z;
    }
}

extern "C" void kernel_launch(void* const* d_in, const int* in_sizes, int n_in,
                              void* d_out, int out_size, void* d_ws, size_t ws_size,
                              hipStream_t stream) {
    const float* x  = (const float*)d_in[0];   // [B,S,D]
    const float* nw = (const float*)d_in[1];   // [D]
    const float* cw = (const float*)d_in[2];   // [D,4]
    const float* pw = (const float*)d_in[3];   // [2,D]
    float* out = (float*)d_out;                // [B,S,D]

    unsigned short* tok = (unsigned short*)d_ws;   // B*S u16 = 32 KB total

    mask_kernel<<<NBLK, 256, 0, stream>>>(x, nw, cw, pw, tok);
    scan_kernel<<<BATCH, 256, 0, stream>>>(tok);
    scatter_kernel<<<BATCH * SEQ, 256, 0, stream>>>(x, tok, out);
}

// Round 3
// 264.179 us; speedup vs baseline: 1.0135x; 1.0135x over previous
//
#include <hip/hip_runtime.h>
#include <cstddef>

#define BATCH 4
#define SEQ   4096
#define DIM   2048
#define EPSF  1e-5f
#define TCHUNK 8
#define CPB   (SEQ / TCHUNK)         // 512 chunks per batch
#define NBLK  (BATCH * CPB)          // 2048 blocks

__device__ __forceinline__ float wave_sum(float v) {
#pragma unroll
    for (int off = 32; off > 0; off >>= 1)
        v += __shfl_down(v, off, 64);
    return v;
}

// Phase 1: fused rmsnorm -> causal depthwise conv(W=4) -> silu -> (p1-p0) dot
// -> sign. gate>0.5 <=> logit1-logit0>0: only the sign of one fused dot is
// needed. One block owns all D=2048 (256 thr x 8 ch), slides over TCHUNK=8
// tokens (3-row register history). 2048 blocks -> 2 residency rounds at
// ~3-4 blocks/CU, so late blocks pipeline behind early ones (latency hiding
// across blocks, not just waves). 4 barriers per block.
// Writes ONLY tok[b*S+s] = selected ? 0x8000 : 0   (u16, 32KB total d_ws).
__global__ __launch_bounds__(256, 3) void mask_kernel(
    const float* __restrict__ x, const float* __restrict__ nw,
    const float* __restrict__ cw, const float* __restrict__ pw,
    unsigned short* __restrict__ tok)
{
    __shared__ float lds_ss[3][4][4];   // [group(2=warmup)][tok-in-group][wave]
    __shared__ float lds_acc[2][4][4];  // write-once slots -> no WAR hazards

    const int t = threadIdx.x, lane = t & 63, wid = t >> 6;
    // XCD swizzle: seq-adjacent chunks -> same XCD (L2 reuse of warm-up rows)
    const int G = gridDim.x;
    const int chunk = (blockIdx.x & 7) * (G >> 3) + (blockIdx.x >> 3);
    const int b  = chunk / CPB;
    const int s0 = (chunk % CPB) * TCHUNK;
    const int d0 = 4 * t, d1 = d0 + 1024;

    // conv*norm folded (cwn), projection diff (pd)
    float cwn[8][4], pd[8];
    {
        float4 n0 = *(const float4*)(nw + d0);
        float4 n1 = *(const float4*)(nw + d1);
        float nv[8] = {n0.x, n0.y, n0.z, n0.w, n1.x, n1.y, n1.z, n1.w};
#pragma unroll
        for (int i = 0; i < 8; ++i) {
            const int d = (i < 4) ? (d0 + i) : (d1 + i - 4);
            float4 c4 = *(const float4*)(cw + 4 * d);
            cwn[i][0] = c4.x * nv[i]; cwn[i][1] = c4.y * nv[i];
            cwn[i][2] = c4.z * nv[i]; cwn[i][3] = c4.w * nv[i];
        }
        float4 a0 = *(const float4*)(pw + d0);
        float4 a1 = *(const float4*)(pw + d1);
        float4 b0 = *(const float4*)(pw + DIM + d0);
        float4 b1 = *(const float4*)(pw + DIM + d1);
        pd[0] = b0.x - a0.x; pd[1] = b0.y - a0.y; pd[2] = b0.z - a0.z; pd[3] = b0.w - a0.w;
        pd[4] = b1.x - a1.x; pd[5] = b1.y - a1.y; pd[6] = b1.z - a1.z; pd[7] = b1.w - a1.w;
    }

    const float* xb = x + (size_t)b * SEQ * DIM;
    float h1[8], h2[8], h3[8];   // normalized rows s-1, s-2, s-3

    // ---- warm-up: tokens s0-3..s0-1 (1 barrier) ----
    {
        float wv[3][8];
#pragma unroll
        for (int w = 0; w < 3; ++w) {
            const int s = s0 - 3 + w;
            if (s >= 0) {
                float4 a = *(const float4*)(xb + (size_t)s * DIM + d0);
                float4 c = *(const float4*)(xb + (size_t)s * DIM + d1);
                wv[w][0]=a.x; wv[w][1]=a.y; wv[w][2]=a.z; wv[w][3]=a.w;
                wv[w][4]=c.x; wv[w][5]=c.y; wv[w][6]=c.z; wv[w][7]=c.w;
            } else {
#pragma unroll
                for (int i = 0; i < 8; ++i) wv[w][i] = 0.f;
            }
            float ss = 0.f;
#pragma unroll
            for (int i = 0; i < 8; ++i) ss += wv[w][i] * wv[w][i];
            ss = wave_sum(ss);
            if (lane == 0) lds_ss[2][w][wid] = ss;
        }
        __syncthreads();
#pragma unroll
        for (int w = 0; w < 3; ++w) {
            const float sum4 = lds_ss[2][w][0] + lds_ss[2][w][1]
                             + lds_ss[2][w][2] + lds_ss[2][w][3];
            const float rstd = 1.0f / sqrtf(sum4 * (1.0f / DIM) + EPSF);
            float* h = (w == 0) ? h3 : (w == 1) ? h2 : h1;
#pragma unroll
            for (int i = 0; i < 8; ++i) h[i] = wv[w][i] * rstd;
        }
    }

    // ---- main: 2 groups of 4 tokens, 1 barrier each + 1 final ----
    int pending = -1;
#pragma unroll
    for (int g = 0; g < 2; ++g) {
        float xv[4][8];
#pragma unroll
        for (int j = 0; j < 4; ++j) {
            const int s = s0 + 4 * g + j;
            float4 a = *(const float4*)(xb + (size_t)s * DIM + d0);
            float4 c = *(const float4*)(xb + (size_t)s * DIM + d1);
            xv[j][0]=a.x; xv[j][1]=a.y; xv[j][2]=a.z; xv[j][3]=a.w;
            xv[j][4]=c.x; xv[j][5]=c.y; xv[j][6]=c.z; xv[j][7]=c.w;
        }
#pragma unroll
        for (int j = 0; j < 4; ++j) {
            float ss = 0.f;
#pragma unroll
            for (int i = 0; i < 8; ++i) ss += xv[j][i] * xv[j][i];
            ss = wave_sum(ss);
            if (lane == 0) lds_ss[g][j][wid] = ss;
        }
        __syncthreads();   // orders: this group's ss writes; prev group's acc writes
        if (pending >= 0 && t < 4) {
            const float a = lds_acc[pending][t][0] + lds_acc[pending][t][1]
                          + lds_acc[pending][t][2] + lds_acc[pending][t][3];
            tok[b * SEQ + s0 + 4 * pending + t] = (a > 0.f) ? 0x8000 : 0;
        }
#pragma unroll
        for (int j = 0; j < 4; ++j) {
            const float sum4 = lds_ss[g][j][0] + lds_ss[g][j][1]
                             + lds_ss[g][j][2] + lds_ss[g][j][3];
            const float rstd = 1.0f / sqrtf(sum4 * (1.0f / DIM) + EPSF);
            float acc = 0.f;
#pragma unroll
            for (int i = 0; i < 8; ++i) {
                const float hc = xv[j][i] * rstd;
                const float y = cwn[i][0] * h3[i] + cwn[i][1] * h2[i]
                              + cwn[i][2] * h1[i] + cwn[i][3] * hc;
                const float sig = 1.0f / (1.0f + __expf(-y));
                acc += (y * sig) * pd[i];
                h3[i] = h2[i]; h2[i] = h1[i]; h1[i] = hc;
            }
            acc = wave_sum(acc);
            if (lane == 0) lds_acc[g][j][wid] = acc;
        }
        pending = g;
    }
    __syncthreads();
    if (t < 4) {
        const float a = lds_acc[1][t][0] + lds_acc[1][t][1]
                      + lds_acc[1][t][2] + lds_acc[1][t][3];
        tok[b * SEQ + s0 + 4 + t] = (a > 0.f) ? 0x8000 : 0;
    }
}

// Phase 2: per-batch inclusive prefix over the selected bits, packed back into
// the SAME u16: bit15 = selected, bits 0..12 = inclusive prefix p[s] (<=4096).
__global__ __launch_bounds__(256) void scan_kernel(unsigned short* __restrict__ tok)
{
    const int b = blockIdx.x, t = threadIdx.x;
    const int PER = SEQ / 256;   // 16
    __shared__ int wtot[4];

    int m[PER], tot = 0;
#pragma unroll
    for (int i = 0; i < PER; ++i) {
        m[i] = tok[b * SEQ + t * PER + i] >> 15;
        tot += m[i];
    }
    const int lane = t & 63, wid = t >> 6;
    int inc = tot;
#pragma unroll
    for (int off = 1; off < 64; off <<= 1) {
        int v = __shfl_up(inc, off, 64);
        if (lane >= off) inc += v;
    }
    if (lane == 63) wtot[wid] = inc;
    __syncthreads();
    int pref = inc - tot;
    for (int w = 0; w < wid; ++w) pref += wtot[w];

    int run = pref;
#pragma unroll
    for (int i = 0; i < PER; ++i) {
        run += m[i];
        tok[b * SEQ + t * PER + i] = (unsigned short)((m[i] << 15) | run);
    }
}

// Phase 3: source-driven scatter. Token (b,s): selected -> dest = p-1 (copy x
// row); unselected -> dest = nsel + s - p (zero row). Bijection onto [0,S):
// every output row written exactly once (d_out is poisoned each call).
__global__ __launch_bounds__(256) void scatter_kernel(
    const float* __restrict__ x, const unsigned short* __restrict__ tok,
    float* __restrict__ out)
{
    const int b = blockIdx.x / SEQ;
    const int s = blockIdx.x - b * SEQ;
    const int t = threadIdx.x;
    const unsigned v    = tok[b * SEQ + s];
    const int     nsel  = tok[b * SEQ + SEQ - 1] & 0x7FFF;
    const int     p     = v & 0x7FFF;
    const int     dest  = (v & 0x8000u) ? (p - 1) : (nsel + s - p);
    float* o = out + ((size_t)b * SEQ + dest) * DIM;
    if (v & 0x8000u) {
        const float* src = x + ((size_t)b * SEQ + s) * DIM;
        *(float4*)(o + 4 * t)        = *(const float4*)(src + 4 * t);
        *(float4*)(o + 4 * t + 1024) = *(const float4*)(src + 4 * t + 1024);
    } else {
        const float4 z = make_float4(0.f, 0.f, 0.f, 0.f);
        *(float4*)(o + 4 * t)        = z;
        *(float4*)(o + 4 * t + 1024) = z;
    }
}

extern "C" void kernel_launch(void* const* d_in, const int* in_sizes, int n_in,
                              void* d_out, int out_size, void* d_ws, size_t ws_size,
                              hipStream_t stream) {
    const float* x  = (const float*)d_in[0];   // [B,S,D]
    const float* nw = (const float*)d_in[1];   // [D]
    const float* cw = (const float*)d_in[2];   // [D,4]
    const float* pw = (const float*)d_in[3];   // [2,D]
    float* out = (float*)d_out;                // [B,S,D]

    unsigned short* tok = (unsigned short*)d_ws;   // B*S u16 = 32 KB total

    mask_kernel<<<NBLK, 256, 0, stream>>>(x, nw, cw, pw, tok);
    scan_kernel<<<BATCH, 256, 0, stream>>>(tok);
    scatter_kernel<<<BATCH * SEQ, 256, 0, stream>>>(x, tok, out);
}